// Round 3
// baseline (1079.690 us; speedup 1.0000x reference)
//
#include <hip/hip_runtime.h>
#include <math.h>
#include <type_traits>

#define DMODEL 1024
#define NSEQ   4096
#define MTOT   16384

typedef unsigned short ushortT;
typedef __attribute__((ext_vector_type(8))) short short8;
typedef __attribute__((ext_vector_type(4))) float f32x4;

__device__ __forceinline__ float gelu_f(float x) {
    return 0.5f * x * (1.0f + erff(x * 0.70710678118654752440f));
}
__device__ __forceinline__ double gelu_d(double x) {
    return 0.5 * x * (1.0 + erf(x * 0.70710678118654752440));
}
__device__ __forceinline__ ushortT f2bf(float f) {
    unsigned u = __float_as_uint(f);
    u += 0x7FFFu + ((u >> 16) & 1u);   // round-to-nearest-even
    return (ushortT)(u >> 16);
}
__device__ __forceinline__ float bf2f(ushortT b) {
    return __uint_as_float(((unsigned)b) << 16);
}
// async global->LDS, 16B per lane; LDS dest = wave-uniform base + lane*16
__device__ __forceinline__ void gload16(const void* g, void* l) {
    __builtin_amdgcn_global_load_lds(
        (const __attribute__((address_space(1))) unsigned*)g,
        (__attribute__((address_space(3))) unsigned*)l, 16, 0, 0);
}

// ---------------- bf16 MFMA GEMM (m97 structure) ----------------
// C = epi(A @ Bt^T [+bias]); A [M,K] bf16 row-major (lda), Bt [N,K] bf16 (ldb).
// GATHER: A is V [MTOT,DMODEL]; logical K=2*DMODEL, k>=DMODEL reads row gidx[m].
enum { EPI_BF16 = 0, EPI_GELU_BIAS_BF16 = 1, EPI_BIAS_F32 = 2, EPI_TRANS_BF16 = 3 };

template<int EPI, bool GATHER>
__global__ __launch_bounds__(256)
void mfma_gemm(const ushortT* __restrict__ A, const ushortT* __restrict__ Bt,
               const float* __restrict__ bias, void* __restrict__ Cv,
               int K, int lda, int ldb, int ldc, const int* __restrict__ gidx)
{
    __shared__ ushortT As[128 * 32];
    __shared__ ushortT Bs[128 * 32];
    const int tid  = threadIdx.x;
    const int lane = tid & 63;
    const int w    = tid >> 6;
    const int wr   = (w >> 1) * 64;
    const int wc   = (w & 1) * 64;
    const int m0   = blockIdx.y * 128;
    const int n0   = blockIdx.x * 128;

    const int lrow = lane >> 2;
    const int lk   = (lane & 3) * 8;

    int grow_g[2];
    if constexpr (GATHER) {
        grow_g[0] = gidx[m0 + w * 32 + lrow];
        grow_g[1] = gidx[m0 + w * 32 + 16 + lrow];
    }

    f32x4 acc[4][4];
    #pragma unroll
    for (int i = 0; i < 4; i++)
        #pragma unroll
        for (int j = 0; j < 4; j++) acc[i][j] = (f32x4){0.f, 0.f, 0.f, 0.f};

    for (int kk = 0; kk < K; kk += 32) {
        #pragma unroll
        for (int i = 0; i < 2; i++) {
            const int ar = w * 32 + i * 16 + lrow;
            const ushortT* ga;
            if constexpr (GATHER) {
                ga = (kk < DMODEL)
                   ? A + (size_t)(m0 + ar) * lda + kk + lk
                   : A + (size_t)grow_g[i] * lda + (kk - DMODEL) + lk;
            } else {
                ga = A + (size_t)(m0 + ar) * lda + kk + lk;
            }
            gload16(ga, &As[(w * 32 + i * 16) * 32]);
            const ushortT* gb = Bt + (size_t)(n0 + w * 32 + i * 16 + lrow) * ldb + kk + lk;
            gload16(gb, &Bs[(w * 32 + i * 16) * 32]);
        }
        __syncthreads();

        const int mi = lane & 15;
        const int ko = (lane >> 4) * 8;
        short8 a[4], b[4];
        #pragma unroll
        for (int i = 0; i < 4; i++)
            a[i] = *(const short8*)&As[(wr + i * 16 + mi) * 32 + ko];
        #pragma unroll
        for (int j = 0; j < 4; j++)
            b[j] = *(const short8*)&Bs[(wc + j * 16 + mi) * 32 + ko];
        #pragma unroll
        for (int i = 0; i < 4; i++)
            #pragma unroll
            for (int j = 0; j < 4; j++)
                acc[i][j] = __builtin_amdgcn_mfma_f32_16x16x32_bf16(a[i], b[j], acc[i][j], 0, 0, 0);
        __syncthreads();
    }

    const int cr = (lane >> 4) * 4;
    const int cc = lane & 15;
    #pragma unroll
    for (int i = 0; i < 4; i++) {
        #pragma unroll
        for (int j = 0; j < 4; j++) {
            const int gr = m0 + wr + i * 16 + cr;
            const int gc = n0 + wc + j * 16 + cc;
            #pragma unroll
            for (int r = 0; r < 4; r++) {
                float v = acc[i][j][r];
                if constexpr (EPI == EPI_GELU_BIAS_BF16) v = gelu_f(v + bias[gc]);
                if constexpr (EPI == EPI_BIAS_F32)       v = v + bias[gc];
                if constexpr (EPI == EPI_BF16 || EPI == EPI_GELU_BIAS_BF16)
                    ((ushortT*)Cv)[(size_t)(gr + r) * ldc + gc] = f2bf(v);
                else if constexpr (EPI == EPI_BIAS_F32)
                    ((float*)Cv)[(size_t)(gr + r) * ldc + gc] = v;
                else
                    ((ushortT*)Cv)[(size_t)gc * ldc + (gr + r)] = f2bf(v);
            }
        }
    }
}

// ---------------- encoder fast path: split-bf16 MFMA (fp32-grade precision) ----
// C[m][n] = gelu_f( (Ah+Al)[m,:] . (Bh+Bl)[n,:] + bias[n] ), dropping Al.Bl term.
// A = h split, [MTOT][1024]; B = W_re1^T split, [512][1024]; C f32 [MTOT][512].
__global__ __launch_bounds__(256)
void enc_gemm(const ushortT* __restrict__ Ah, const ushortT* __restrict__ Al,
              const ushortT* __restrict__ Bh, const ushortT* __restrict__ Bl,
              const float* __restrict__ bias, float* __restrict__ C)
{
    __shared__ ushortT Ash[128 * 32], Asl[128 * 32];
    __shared__ ushortT Bsh[128 * 32], Bsl[128 * 32];
    const int tid  = threadIdx.x;
    const int lane = tid & 63;
    const int w    = tid >> 6;
    const int wr   = (w >> 1) * 64;
    const int wc   = (w & 1) * 64;
    const int m0   = blockIdx.y * 128;
    const int n0   = blockIdx.x * 128;
    const int lrow = lane >> 2;
    const int lk   = (lane & 3) * 8;

    f32x4 acc[4][4];
    #pragma unroll
    for (int i = 0; i < 4; i++)
        #pragma unroll
        for (int j = 0; j < 4; j++) acc[i][j] = (f32x4){0.f, 0.f, 0.f, 0.f};

    for (int kk = 0; kk < DMODEL; kk += 32) {
        #pragma unroll
        for (int i = 0; i < 2; i++) {
            const size_t aoff = (size_t)(m0 + w * 32 + i * 16 + lrow) * DMODEL + kk + lk;
            const size_t boff = (size_t)(n0 + w * 32 + i * 16 + lrow) * DMODEL + kk + lk;
            const int ldst = (w * 32 + i * 16) * 32;
            gload16(Ah + aoff, &Ash[ldst]);
            gload16(Al + aoff, &Asl[ldst]);
            gload16(Bh + boff, &Bsh[ldst]);
            gload16(Bl + boff, &Bsl[ldst]);
        }
        __syncthreads();

        const int mi = lane & 15;
        const int ko = (lane >> 4) * 8;
        short8 ah[4], al[4], bh[4], bl[4];
        #pragma unroll
        for (int i = 0; i < 4; i++) {
            ah[i] = *(const short8*)&Ash[(wr + i * 16 + mi) * 32 + ko];
            al[i] = *(const short8*)&Asl[(wr + i * 16 + mi) * 32 + ko];
        }
        #pragma unroll
        for (int j = 0; j < 4; j++) {
            bh[j] = *(const short8*)&Bsh[(wc + j * 16 + mi) * 32 + ko];
            bl[j] = *(const short8*)&Bsl[(wc + j * 16 + mi) * 32 + ko];
        }
        #pragma unroll
        for (int i = 0; i < 4; i++)
            #pragma unroll
            for (int j = 0; j < 4; j++) {
                acc[i][j] = __builtin_amdgcn_mfma_f32_16x16x32_bf16(ah[i], bh[j], acc[i][j], 0, 0, 0);
                acc[i][j] = __builtin_amdgcn_mfma_f32_16x16x32_bf16(ah[i], bl[j], acc[i][j], 0, 0, 0);
                acc[i][j] = __builtin_amdgcn_mfma_f32_16x16x32_bf16(al[i], bh[j], acc[i][j], 0, 0, 0);
            }
        __syncthreads();
    }

    const int cr = (lane >> 4) * 4;
    const int cc = lane & 15;
    #pragma unroll
    for (int i = 0; i < 4; i++)
        #pragma unroll
        for (int j = 0; j < 4; j++) {
            const int gr = m0 + wr + i * 16 + cr;
            const int gc = n0 + wc + j * 16 + cc;
            #pragma unroll
            for (int r = 0; r < 4; r++)
                C[(size_t)(gr + r) * 512 + gc] = gelu_f(acc[i][j][r] + bias[gc]);
        }
}

// logit = gelu_row . W_re2 (fp64 accum of f32 values); flag borderline tokens
__global__ __launch_bounds__(256)
void target2_k(const float* __restrict__ Genc, const float* __restrict__ W2,
               const float* __restrict__ b2, float* __restrict__ outT,
               float* __restrict__ outS, int* __restrict__ gidx,
               int* __restrict__ cnt, int* __restrict__ list)
{
    const int m = blockIdx.x * 4 + (threadIdx.x >> 6);
    const int lane = threadIdx.x & 63;
    const float* gr = Genc + (size_t)m * 512;
    double s = 0.0;
    #pragma unroll 4
    for (int j = lane; j < 512; j += 64) s = fma((double)gr[j], (double)W2[j], s);
    #pragma unroll
    for (int off = 32; off; off >>= 1) s += __shfl_down(s, off);
    if (lane == 0) {
        double logit = s + (double)b2[0];
        double str = 1.0 / (1.0 + exp(-logit));
        double r = str * (double)(NSEQ - 1);
        double n = rint(r);
        double dist = fabs(r - n);             // distance to nearest integer
        n = fmin(fmax(n, 0.0), (double)(NSEQ - 1));
        int t = (int)n;
        outT[m] = (float)t;
        outS[m] = (float)str;
        gidx[m] = ((m >> 12) << 12) + t;
        if (dist > 0.46) {                      // within 0.04 of a .5 boundary
            int ix = atomicAdd(cnt, 1);
            list[ix] = m;
        }
    }
}

// exact fp64 recompute for flagged tokens (8 per block iteration)
__global__ __launch_bounds__(256)
void fixup_k(const float* __restrict__ h, const float* __restrict__ W1,
             const float* __restrict__ b1, const float* __restrict__ W2,
             const float* __restrict__ b2, const int* __restrict__ cnt_p,
             const int* __restrict__ list, float* __restrict__ outT,
             float* __restrict__ outS, int* __restrict__ gidx)
{
    __shared__ float hrow[8][1024];
    __shared__ double red[4][8];
    const int tid = threadIdx.x;
    const int cnt = *cnt_p;
    for (int base = blockIdx.x * 8; base < cnt; base += 256 * 8) {
        const int nt = min(8, cnt - base);
        for (int t = 0; t < nt; t++) {
            const int m = list[base + t];
            for (int k = tid; k < 1024; k += 256)
                hrow[t][k] = h[(size_t)m * 1024 + k];
        }
        __syncthreads();
        double a0[8], a1[8];
        #pragma unroll
        for (int t = 0; t < 8; t++) { a0[t] = 0.0; a1[t] = 0.0; }
        for (int k = 0; k < 1024; k++) {
            const double wa = (double)W1[(size_t)k * 512 + tid];
            const double wb = (double)W1[(size_t)k * 512 + tid + 256];
            #pragma unroll
            for (int t = 0; t < 8; t++) {
                const double hv = (double)hrow[t][k];
                a0[t] = fma(hv, wa, a0[t]);
                a1[t] = fma(hv, wb, a1[t]);
            }
        }
        const double w2a = (double)W2[tid], w2b = (double)W2[tid + 256];
        const double b1a = (double)b1[tid], b1b = (double)b1[tid + 256];
        const int lane = tid & 63, w = tid >> 6;
        #pragma unroll
        for (int t = 0; t < 8; t++) {
            double v = w2a * gelu_d(a0[t] + b1a) + w2b * gelu_d(a1[t] + b1b);
            #pragma unroll
            for (int off = 32; off; off >>= 1) v += __shfl_down(v, off);
            if (lane == 0) red[w][t] = v;
        }
        __syncthreads();
        if (tid < nt) {
            const int t = tid;
            double logit = red[0][t] + red[1][t] + red[2][t] + red[3][t] + (double)b2[0];
            double str = 1.0 / (1.0 + exp(-logit));
            double r = str * (double)(NSEQ - 1);
            double n = rint(r);
            n = fmin(fmax(n, 0.0), (double)(NSEQ - 1));
            const int m = list[base + t];
            const int ti = (int)n;
            outT[m] = (float)ti;
            outS[m] = (float)str;
            gidx[m] = ((m >> 12) << 12) + ti;
        }
        __syncthreads();
    }
}

__global__ __launch_bounds__(256)
void biascomb_k(const float* __restrict__ brt2, const float* __restrict__ Wo,
                float* __restrict__ bc)
{
    int j = blockIdx.x * 256 + threadIdx.x;
    float s = 0.f;
    for (int e = 0; e < DMODEL; e++) s = fmaf(brt2[e], Wo[e * DMODEL + j], s);
    bc[j] = s;
}

// f32 -> bf16 straight cast
__global__ __launch_bounds__(256)
void cast_k(const float* __restrict__ x, ushortT* __restrict__ y, int n)
{
    int i = (blockIdx.x * 256 + threadIdx.x) * 4;
    if (i < n) {
        float4 v = *(const float4*)(x + i);
        ushortT o[4] = { f2bf(v.x), f2bf(v.y), f2bf(v.z), f2bf(v.w) };
        *(ulong1*)&y[i] = *(ulong1*)o;
    }
}

// f32 -> (hi bf16, lo bf16) 2-way split
__global__ __launch_bounds__(256)
void split_cast_k(const float* __restrict__ x, ushortT* __restrict__ yh,
                  ushortT* __restrict__ yl, int n)
{
    int i = (blockIdx.x * 256 + threadIdx.x) * 4;
    if (i < n) {
        float4 v = *(const float4*)(x + i);
        float vv[4] = { v.x, v.y, v.z, v.w };
        ushortT oh[4], ol[4];
        #pragma unroll
        for (int q = 0; q < 4; q++) {
            oh[q] = f2bf(vv[q]);
            ol[q] = f2bf(vv[q] - bf2f(oh[q]));
        }
        *(ulong1*)&yh[i] = *(ulong1*)oh;
        *(ulong1*)&yl[i] = *(ulong1*)ol;
    }
}

// W [K][N] f32 -> Wt [N][K] bf16
__global__ __launch_bounds__(256)
void transcast_k(const float* __restrict__ W, ushortT* __restrict__ Wt, int K, int N)
{
    __shared__ float t[32][33];
    const int tx = threadIdx.x & 31, ty = threadIdx.x >> 5;
    const int n0 = blockIdx.x * 32, k0 = blockIdx.y * 32;
    #pragma unroll
    for (int r = 0; r < 32; r += 8)
        t[ty + r][tx] = W[(size_t)(k0 + ty + r) * N + n0 + tx];
    __syncthreads();
    #pragma unroll
    for (int r = 0; r < 32; r += 8)
        Wt[(size_t)(n0 + ty + r) * K + k0 + tx] = f2bf(t[tx][ty + r]);
}

// W [K][N] f32 -> Wt_hi/lo [N][K] bf16 split
__global__ __launch_bounds__(256)
void split_transcast_k(const float* __restrict__ W, ushortT* __restrict__ Wth,
                       ushortT* __restrict__ Wtl, int K, int N)
{
    __shared__ float t[32][33];
    const int tx = threadIdx.x & 31, ty = threadIdx.x >> 5;
    const int n0 = blockIdx.x * 32, k0 = blockIdx.y * 32;
    #pragma unroll
    for (int r = 0; r < 32; r += 8)
        t[ty + r][tx] = W[(size_t)(k0 + ty + r) * N + n0 + tx];
    __syncthreads();
    #pragma unroll
    for (int r = 0; r < 32; r += 8) {
        float x = t[tx][ty + r];
        ushortT hi = f2bf(x);
        Wth[(size_t)(n0 + ty + r) * K + k0 + tx] = hi;
        Wtl[(size_t)(n0 + ty + r) * K + k0 + tx] = f2bf(x - bf2f(hi));
    }
}

extern "C" void kernel_launch(void* const* d_in, const int* in_sizes, int n_in,
                              void* d_out, int out_size, void* d_ws, size_t ws_size,
                              hipStream_t stream)
{
    const float* h     = (const float*)d_in[0];
    const float* W_re1 = (const float*)d_in[1];
    const float* b_re1 = (const float*)d_in[2];
    const float* W_re2 = (const float*)d_in[3];
    const float* b_re2 = (const float*)d_in[4];
    const float* W_v   = (const float*)d_in[5];
    const float* W_rt1 = (const float*)d_in[6];
    const float* b_rt1 = (const float*)d_in[7];
    const float* W_rt2 = (const float*)d_in[8];
    const float* b_rt2 = (const float*)d_in[9];
    const float* W_o   = (const float*)d_in[10];

    float* z    = (float*)d_out;                        // [16384,1024] f32
    float* outT = z + (size_t)MTOT * DMODEL;
    float* outS = outT + MTOT;
    ushortT* V    = (ushortT*)z;                        // bf16, lower 32 MB of z region
    ushortT* h_hi = (ushortT*)z + (size_t)MTOT * DMODEL;// bf16, upper 32 MB of z region

    char* ws = (char*)d_ws;
    ushortT* G       = (ushortT*)ws;                          // 32 MB
    float*   Genc    = (float*)(ws + (32ull  << 20));         // 32 MB  gelu(pre) f32
    ushortT* h_lo    = (ushortT*)(ws + (64ull  << 20));       // 32 MB
    ushortT* Wv_t    = (ushortT*)(ws + (96ull  << 20));       // 2 MB
    ushortT* Wrt1_t  = (ushortT*)(ws + (98ull  << 20));       // 4 MB
    ushortT* Wo_t    = (ushortT*)(ws + (102ull << 20));       // 2 MB
    ushortT* Wrt2_b  = (ushortT*)(ws + (104ull << 20));       // 2 MB
    ushortT* Wc_t    = (ushortT*)(ws + (106ull << 20));       // 2 MB
    ushortT* Wre1t_h = (ushortT*)(ws + (108ull << 20));       // 1 MB [512][1024]
    ushortT* Wre1t_l = (ushortT*)(ws + (109ull << 20));       // 1 MB
    float*   b_c     = (float*)(ws + (110ull << 20));         // 4 KB
    int*     cnt     = (int*)  (ws + (110ull << 20) + 4096);  // 4 KB
    int*     gidx    = (int*)  (ws + (110ull << 20) + 8192);  // 64 KB
    int*     list    = (int*)  (ws + (110ull << 20) + 8192 + 65536); // 64 KB

    // --- casts / splits / transposes ---
    split_cast_k<<<dim3(MTOT * DMODEL / 1024), 256, 0, stream>>>(h, h_hi, h_lo, MTOT * DMODEL);
    split_transcast_k<<<dim3(16, 32), 256, 0, stream>>>(W_re1, Wre1t_h, Wre1t_l, DMODEL, 512);
    cast_k<<<dim3(DMODEL * DMODEL / 1024), 256, 0, stream>>>(W_rt2, Wrt2_b, DMODEL * DMODEL);
    transcast_k<<<dim3(32, 32), 256, 0, stream>>>(W_v, Wv_t, DMODEL, DMODEL);
    transcast_k<<<dim3(32, 64), 256, 0, stream>>>(W_rt1, Wrt1_t, 2 * DMODEL, DMODEL);
    transcast_k<<<dim3(32, 32), 256, 0, stream>>>(W_o, Wo_t, DMODEL, DMODEL);
    biascomb_k<<<dim3(4), 256, 0, stream>>>(b_rt2, W_o, b_c);

    // --- encoder fast path (split-bf16 MFMA, fp32-grade) ---
    enc_gemm<<<dim3(4, 128), 256, 0, stream>>>(h_hi, h_lo, Wre1t_h, Wre1t_l, b_re1, Genc);

    hipMemsetAsync(cnt, 0, 4, stream);
    target2_k<<<dim3(MTOT / 4), 256, 0, stream>>>(Genc, W_re2, b_re2, outT, outS, gidx, cnt, list);
    // exact fp64 recompute of borderline tokens (~8%)
    fixup_k<<<dim3(256), 256, 0, stream>>>(h, W_re1, b_re1, W_re2, b_re2, cnt, list,
                                           outT, outS, gidx);

    // --- z path (unchanged from round 2) ---
    mfma_gemm<EPI_TRANS_BF16, false><<<dim3(8, 8), 256, 0, stream>>>(
        Wrt2_b, Wo_t, nullptr, (void*)Wc_t, DMODEL, DMODEL, DMODEL, DMODEL, nullptr);

    mfma_gemm<EPI_BF16, false><<<dim3(8, 128), 256, 0, stream>>>(
        h_hi, Wv_t, nullptr, (void*)V, DMODEL, DMODEL, DMODEL, DMODEL, nullptr);

    mfma_gemm<EPI_GELU_BIAS_BF16, true><<<dim3(8, 128), 256, 0, stream>>>(
        V, Wrt1_t, b_rt1, (void*)G, 2 * DMODEL, DMODEL, 2 * DMODEL, DMODEL, gidx);

    mfma_gemm<EPI_BIAS_F32, false><<<dim3(8, 128), 256, 0, stream>>>(
        G, Wc_t, b_c, (void*)z, DMODEL, DMODEL, DMODEL, DMODEL, nullptr);
}

// Round 4
// 655.104 us; speedup vs baseline: 1.6481x; 1.6481x over previous
//
#include <hip/hip_runtime.h>
#include <math.h>
#include <type_traits>

#define DMODEL 1024
#define NSEQ   4096
#define MTOT   16384

typedef unsigned short ushortT;
typedef __attribute__((ext_vector_type(8))) short short8;
typedef __attribute__((ext_vector_type(4))) float f32x4;

__device__ __forceinline__ float gelu_f(float x) {
    return 0.5f * x * (1.0f + erff(x * 0.70710678118654752440f));
}
__device__ __forceinline__ double gelu_d(double x) {
    return 0.5 * x * (1.0 + erf(x * 0.70710678118654752440));
}
__device__ __forceinline__ ushortT f2bf(float f) {
    unsigned u = __float_as_uint(f);
    u += 0x7FFFu + ((u >> 16) & 1u);   // round-to-nearest-even
    return (ushortT)(u >> 16);
}
__device__ __forceinline__ float bf2f(ushortT b) {
    return __uint_as_float(((unsigned)b) << 16);
}
// async global->LDS, 16B per lane; LDS dest = wave-uniform base + lane*16
__device__ __forceinline__ void gload16(const void* g, void* l) {
    __builtin_amdgcn_global_load_lds(
        (const __attribute__((address_space(1))) unsigned*)g,
        (__attribute__((address_space(3))) unsigned*)l, 16, 0, 0);
}

// ---------------- bf16 MFMA GEMM (m97 structure) ----------------
// C = epi(A @ Bt^T [+bias]); A [M,K] bf16 row-major (lda), Bt [N,K] bf16 (ldb).
// GATHER: A is V [MTOT,DMODEL]; logical K=2*DMODEL, k>=DMODEL reads row gidx[m].
enum { EPI_BF16 = 0, EPI_GELU_BIAS_BF16 = 1, EPI_BIAS_F32 = 2, EPI_TRANS_BF16 = 3 };

template<int EPI, bool GATHER>
__global__ __launch_bounds__(256)
void mfma_gemm(const ushortT* __restrict__ A, const ushortT* __restrict__ Bt,
               const float* __restrict__ bias, void* __restrict__ Cv,
               int K, int lda, int ldb, int ldc, const int* __restrict__ gidx)
{
    __shared__ ushortT As[128 * 32];
    __shared__ ushortT Bs[128 * 32];
    const int tid  = threadIdx.x;
    const int lane = tid & 63;
    const int w    = tid >> 6;
    const int wr   = (w >> 1) * 64;
    const int wc   = (w & 1) * 64;
    const int m0   = blockIdx.y * 128;
    const int n0   = blockIdx.x * 128;

    const int lrow = lane >> 2;
    const int lk   = (lane & 3) * 8;

    int grow_g[2];
    if constexpr (GATHER) {
        grow_g[0] = gidx[m0 + w * 32 + lrow];
        grow_g[1] = gidx[m0 + w * 32 + 16 + lrow];
    }

    f32x4 acc[4][4];
    #pragma unroll
    for (int i = 0; i < 4; i++)
        #pragma unroll
        for (int j = 0; j < 4; j++) acc[i][j] = (f32x4){0.f, 0.f, 0.f, 0.f};

    for (int kk = 0; kk < K; kk += 32) {
        #pragma unroll
        for (int i = 0; i < 2; i++) {
            const int ar = w * 32 + i * 16 + lrow;
            const ushortT* ga;
            if constexpr (GATHER) {
                ga = (kk < DMODEL)
                   ? A + (size_t)(m0 + ar) * lda + kk + lk
                   : A + (size_t)grow_g[i] * lda + (kk - DMODEL) + lk;
            } else {
                ga = A + (size_t)(m0 + ar) * lda + kk + lk;
            }
            gload16(ga, &As[(w * 32 + i * 16) * 32]);
            const ushortT* gb = Bt + (size_t)(n0 + w * 32 + i * 16 + lrow) * ldb + kk + lk;
            gload16(gb, &Bs[(w * 32 + i * 16) * 32]);
        }
        __syncthreads();

        const int mi = lane & 15;
        const int ko = (lane >> 4) * 8;
        short8 a[4], b[4];
        #pragma unroll
        for (int i = 0; i < 4; i++)
            a[i] = *(const short8*)&As[(wr + i * 16 + mi) * 32 + ko];
        #pragma unroll
        for (int j = 0; j < 4; j++)
            b[j] = *(const short8*)&Bs[(wc + j * 16 + mi) * 32 + ko];
        #pragma unroll
        for (int i = 0; i < 4; i++)
            #pragma unroll
            for (int j = 0; j < 4; j++)
                acc[i][j] = __builtin_amdgcn_mfma_f32_16x16x32_bf16(a[i], b[j], acc[i][j], 0, 0, 0);
        __syncthreads();
    }

    const int cr = (lane >> 4) * 4;
    const int cc = lane & 15;
    #pragma unroll
    for (int i = 0; i < 4; i++) {
        #pragma unroll
        for (int j = 0; j < 4; j++) {
            const int gr = m0 + wr + i * 16 + cr;
            const int gc = n0 + wc + j * 16 + cc;
            #pragma unroll
            for (int r = 0; r < 4; r++) {
                float v = acc[i][j][r];
                if constexpr (EPI == EPI_GELU_BIAS_BF16) v = gelu_f(v + bias[gc]);
                if constexpr (EPI == EPI_BIAS_F32)       v = v + bias[gc];
                if constexpr (EPI == EPI_BF16 || EPI == EPI_GELU_BIAS_BF16)
                    ((ushortT*)Cv)[(size_t)(gr + r) * ldc + gc] = f2bf(v);
                else if constexpr (EPI == EPI_BIAS_F32)
                    ((float*)Cv)[(size_t)(gr + r) * ldc + gc] = v;
                else
                    ((ushortT*)Cv)[(size_t)gc * ldc + (gr + r)] = f2bf(v);
            }
        }
    }
}

// ---------------- encoder fast path: split-bf16 MFMA (fp32-grade precision) ----
__global__ __launch_bounds__(256)
void enc_gemm(const ushortT* __restrict__ Ah, const ushortT* __restrict__ Al,
              const ushortT* __restrict__ Bh, const ushortT* __restrict__ Bl,
              const float* __restrict__ bias, float* __restrict__ C)
{
    __shared__ ushortT Ash[128 * 32], Asl[128 * 32];
    __shared__ ushortT Bsh[128 * 32], Bsl[128 * 32];
    const int tid  = threadIdx.x;
    const int lane = tid & 63;
    const int w    = tid >> 6;
    const int wr   = (w >> 1) * 64;
    const int wc   = (w & 1) * 64;
    const int m0   = blockIdx.y * 128;
    const int n0   = blockIdx.x * 128;
    const int lrow = lane >> 2;
    const int lk   = (lane & 3) * 8;

    f32x4 acc[4][4];
    #pragma unroll
    for (int i = 0; i < 4; i++)
        #pragma unroll
        for (int j = 0; j < 4; j++) acc[i][j] = (f32x4){0.f, 0.f, 0.f, 0.f};

    for (int kk = 0; kk < DMODEL; kk += 32) {
        #pragma unroll
        for (int i = 0; i < 2; i++) {
            const size_t aoff = (size_t)(m0 + w * 32 + i * 16 + lrow) * DMODEL + kk + lk;
            const size_t boff = (size_t)(n0 + w * 32 + i * 16 + lrow) * DMODEL + kk + lk;
            const int ldst = (w * 32 + i * 16) * 32;
            gload16(Ah + aoff, &Ash[ldst]);
            gload16(Al + aoff, &Asl[ldst]);
            gload16(Bh + boff, &Bsh[ldst]);
            gload16(Bl + boff, &Bsl[ldst]);
        }
        __syncthreads();

        const int mi = lane & 15;
        const int ko = (lane >> 4) * 8;
        short8 ah[4], al[4], bh[4], bl[4];
        #pragma unroll
        for (int i = 0; i < 4; i++) {
            ah[i] = *(const short8*)&Ash[(wr + i * 16 + mi) * 32 + ko];
            al[i] = *(const short8*)&Asl[(wr + i * 16 + mi) * 32 + ko];
        }
        #pragma unroll
        for (int j = 0; j < 4; j++) {
            bh[j] = *(const short8*)&Bsh[(wc + j * 16 + mi) * 32 + ko];
            bl[j] = *(const short8*)&Bsl[(wc + j * 16 + mi) * 32 + ko];
        }
        #pragma unroll
        for (int i = 0; i < 4; i++)
            #pragma unroll
            for (int j = 0; j < 4; j++) {
                acc[i][j] = __builtin_amdgcn_mfma_f32_16x16x32_bf16(ah[i], bh[j], acc[i][j], 0, 0, 0);
                acc[i][j] = __builtin_amdgcn_mfma_f32_16x16x32_bf16(ah[i], bl[j], acc[i][j], 0, 0, 0);
                acc[i][j] = __builtin_amdgcn_mfma_f32_16x16x32_bf16(al[i], bh[j], acc[i][j], 0, 0, 0);
            }
        __syncthreads();
    }

    const int cr = (lane >> 4) * 4;
    const int cc = lane & 15;
    #pragma unroll
    for (int i = 0; i < 4; i++)
        #pragma unroll
        for (int j = 0; j < 4; j++) {
            const int gr = m0 + wr + i * 16 + cr;
            const int gc = n0 + wc + j * 16 + cc;
            #pragma unroll
            for (int r = 0; r < 4; r++)
                C[(size_t)(gr + r) * 512 + gc] = gelu_f(acc[i][j][r] + bias[gc]);
        }
}

// logit = gelu_row . W_re2 (fp64 accum of f32 values); flag borderline tokens
__global__ __launch_bounds__(256)
void target2_k(const float* __restrict__ Genc, const float* __restrict__ W2,
               const float* __restrict__ b2, float* __restrict__ outT,
               float* __restrict__ outS, int* __restrict__ gidx,
               int* __restrict__ cnt, int* __restrict__ list)
{
    const int m = blockIdx.x * 4 + (threadIdx.x >> 6);
    const int lane = threadIdx.x & 63;
    const float* gr = Genc + (size_t)m * 512;
    double s = 0.0;
    #pragma unroll 4
    for (int j = lane; j < 512; j += 64) s = fma((double)gr[j], (double)W2[j], s);
    #pragma unroll
    for (int off = 32; off; off >>= 1) s += __shfl_down(s, off);
    if (lane == 0) {
        double logit = s + (double)b2[0];
        double str = 1.0 / (1.0 + exp(-logit));
        double r = str * (double)(NSEQ - 1);
        double n = rint(r);
        double dist = fabs(r - n);             // distance to nearest integer
        n = fmin(fmax(n, 0.0), (double)(NSEQ - 1));
        int t = (int)n;
        outT[m] = (float)t;
        outS[m] = (float)str;
        gidx[m] = ((m >> 12) << 12) + t;
        if (dist > 0.46) {                      // within 0.04 of a .5 boundary
            int ix = atomicAdd(cnt, 1);
            list[ix] = m;
        }
    }
}

// exact fp64 recompute for flagged tokens.
// v2: 2 tokens/block, grid 4096 -> ~650 active blocks (2.5/CU, 2.5 waves/SIMD)
// vs v1's 163 blocks (1 wave/SIMD, latency-starved at 527 us).
#define FIX_T 2
__global__ __launch_bounds__(256)
void fixup_k(const float* __restrict__ h, const float* __restrict__ W1,
             const float* __restrict__ b1, const float* __restrict__ W2,
             const float* __restrict__ b2, const int* __restrict__ cnt_p,
             const int* __restrict__ list, float* __restrict__ outT,
             float* __restrict__ outS, int* __restrict__ gidx)
{
    __shared__ float hrow[FIX_T][1024];
    __shared__ double red[4][FIX_T];
    const int tid = threadIdx.x;
    const int cnt = *cnt_p;
    for (int base = (int)blockIdx.x * FIX_T; base < cnt;
         base += (int)gridDim.x * FIX_T) {
        const int nt = min(FIX_T, cnt - base);
        for (int t = 0; t < nt; t++) {
            const int m = list[base + t];
            const float4* src = (const float4*)(h + (size_t)m * 1024);
            ((float4*)hrow[t])[tid] = src[tid];   // 256 * 16B = 4 KB row
        }
        __syncthreads();

        double a[FIX_T][2];
        #pragma unroll
        for (int t = 0; t < FIX_T; t++) { a[t][0] = 0.0; a[t][1] = 0.0; }

        #pragma unroll 4
        for (int k = 0; k < 1024; k++) {
            const double wa = (double)W1[(size_t)k * 512 + tid];
            const double wb = (double)W1[(size_t)k * 512 + tid + 256];
            #pragma unroll
            for (int t = 0; t < FIX_T; t++) {
                const double hv = (double)hrow[t][k];
                a[t][0] = fma(hv, wa, a[t][0]);
                a[t][1] = fma(hv, wb, a[t][1]);
            }
        }

        const double w2a = (double)W2[tid], w2b = (double)W2[tid + 256];
        const double b1a = (double)b1[tid], b1b = (double)b1[tid + 256];
        const int lane = tid & 63, w = tid >> 6;
        #pragma unroll
        for (int t = 0; t < FIX_T; t++) {
            double v = w2a * gelu_d(a[t][0] + b1a) + w2b * gelu_d(a[t][1] + b1b);
            #pragma unroll
            for (int off = 32; off; off >>= 1) v += __shfl_down(v, off);
            if (lane == 0) red[w][t] = v;
        }
        __syncthreads();
        if (tid < nt) {
            const int t = tid;
            double logit = red[0][t] + red[1][t] + red[2][t] + red[3][t] + (double)b2[0];
            double str = 1.0 / (1.0 + exp(-logit));
            double r = str * (double)(NSEQ - 1);
            double n = rint(r);
            n = fmin(fmax(n, 0.0), (double)(NSEQ - 1));
            const int m = list[base + t];
            const int ti = (int)n;
            outT[m] = (float)ti;
            outS[m] = (float)str;
            gidx[m] = ((m >> 12) << 12) + ti;
        }
        __syncthreads();
    }
}

__global__ __launch_bounds__(256)
void biascomb_k(const float* __restrict__ brt2, const float* __restrict__ Wo,
                float* __restrict__ bc)
{
    int j = blockIdx.x * 256 + threadIdx.x;
    float s = 0.f;
    for (int e = 0; e < DMODEL; e++) s = fmaf(brt2[e], Wo[e * DMODEL + j], s);
    bc[j] = s;
}

// f32 -> bf16 straight cast
__global__ __launch_bounds__(256)
void cast_k(const float* __restrict__ x, ushortT* __restrict__ y, int n)
{
    int i = (blockIdx.x * 256 + threadIdx.x) * 4;
    if (i < n) {
        float4 v = *(const float4*)(x + i);
        ushortT o[4] = { f2bf(v.x), f2bf(v.y), f2bf(v.z), f2bf(v.w) };
        *(ulong1*)&y[i] = *(ulong1*)o;
    }
}

// f32 -> (hi bf16, lo bf16) 2-way split
__global__ __launch_bounds__(256)
void split_cast_k(const float* __restrict__ x, ushortT* __restrict__ yh,
                  ushortT* __restrict__ yl, int n)
{
    int i = (blockIdx.x * 256 + threadIdx.x) * 4;
    if (i < n) {
        float4 v = *(const float4*)(x + i);
        float vv[4] = { v.x, v.y, v.z, v.w };
        ushortT oh[4], ol[4];
        #pragma unroll
        for (int q = 0; q < 4; q++) {
            oh[q] = f2bf(vv[q]);
            ol[q] = f2bf(vv[q] - bf2f(oh[q]));
        }
        *(ulong1*)&yh[i] = *(ulong1*)oh;
        *(ulong1*)&yl[i] = *(ulong1*)ol;
    }
}

// W [K][N] f32 -> Wt [N][K] bf16
__global__ __launch_bounds__(256)
void transcast_k(const float* __restrict__ W, ushortT* __restrict__ Wt, int K, int N)
{
    __shared__ float t[32][33];
    const int tx = threadIdx.x & 31, ty = threadIdx.x >> 5;
    const int n0 = blockIdx.x * 32, k0 = blockIdx.y * 32;
    #pragma unroll
    for (int r = 0; r < 32; r += 8)
        t[ty + r][tx] = W[(size_t)(k0 + ty + r) * N + n0 + tx];
    __syncthreads();
    #pragma unroll
    for (int r = 0; r < 32; r += 8)
        Wt[(size_t)(n0 + ty + r) * K + k0 + tx] = f2bf(t[tx][ty + r]);
}

// W [K][N] f32 -> Wt_hi/lo [N][K] bf16 split
__global__ __launch_bounds__(256)
void split_transcast_k(const float* __restrict__ W, ushortT* __restrict__ Wth,
                       ushortT* __restrict__ Wtl, int K, int N)
{
    __shared__ float t[32][33];
    const int tx = threadIdx.x & 31, ty = threadIdx.x >> 5;
    const int n0 = blockIdx.x * 32, k0 = blockIdx.y * 32;
    #pragma unroll
    for (int r = 0; r < 32; r += 8)
        t[ty + r][tx] = W[(size_t)(k0 + ty + r) * N + n0 + tx];
    __syncthreads();
    #pragma unroll
    for (int r = 0; r < 32; r += 8) {
        float x = t[tx][ty + r];
        ushortT hi = f2bf(x);
        Wth[(size_t)(n0 + ty + r) * K + k0 + tx] = hi;
        Wtl[(size_t)(n0 + ty + r) * K + k0 + tx] = f2bf(x - bf2f(hi));
    }
}

extern "C" void kernel_launch(void* const* d_in, const int* in_sizes, int n_in,
                              void* d_out, int out_size, void* d_ws, size_t ws_size,
                              hipStream_t stream)
{
    const float* h     = (const float*)d_in[0];
    const float* W_re1 = (const float*)d_in[1];
    const float* b_re1 = (const float*)d_in[2];
    const float* W_re2 = (const float*)d_in[3];
    const float* b_re2 = (const float*)d_in[4];
    const float* W_v   = (const float*)d_in[5];
    const float* W_rt1 = (const float*)d_in[6];
    const float* b_rt1 = (const float*)d_in[7];
    const float* W_rt2 = (const float*)d_in[8];
    const float* b_rt2 = (const float*)d_in[9];
    const float* W_o   = (const float*)d_in[10];

    float* z    = (float*)d_out;                        // [16384,1024] f32
    float* outT = z + (size_t)MTOT * DMODEL;
    float* outS = outT + MTOT;
    ushortT* V    = (ushortT*)z;                        // bf16, lower 32 MB of z region
    ushortT* h_hi = (ushortT*)z + (size_t)MTOT * DMODEL;// bf16, upper 32 MB of z region

    char* ws = (char*)d_ws;
    ushortT* G       = (ushortT*)ws;                          // 32 MB
    float*   Genc    = (float*)(ws + (32ull  << 20));         // 32 MB  gelu(pre) f32
    ushortT* h_lo    = (ushortT*)(ws + (64ull  << 20));       // 32 MB
    ushortT* Wv_t    = (ushortT*)(ws + (96ull  << 20));       // 2 MB
    ushortT* Wrt1_t  = (ushortT*)(ws + (98ull  << 20));       // 4 MB
    ushortT* Wo_t    = (ushortT*)(ws + (102ull << 20));       // 2 MB
    ushortT* Wrt2_b  = (ushortT*)(ws + (104ull << 20));       // 2 MB
    ushortT* Wc_t    = (ushortT*)(ws + (106ull << 20));       // 2 MB
    ushortT* Wre1t_h = (ushortT*)(ws + (108ull << 20));       // 1 MB [512][1024]
    ushortT* Wre1t_l = (ushortT*)(ws + (109ull << 20));       // 1 MB
    float*   b_c     = (float*)(ws + (110ull << 20));         // 4 KB
    int*     cnt     = (int*)  (ws + (110ull << 20) + 4096);  // 4 KB
    int*     gidx    = (int*)  (ws + (110ull << 20) + 8192);  // 64 KB
    int*     list    = (int*)  (ws + (110ull << 20) + 8192 + 65536); // 64 KB

    // --- casts / splits / transposes ---
    split_cast_k<<<dim3(MTOT * DMODEL / 1024), 256, 0, stream>>>(h, h_hi, h_lo, MTOT * DMODEL);
    split_transcast_k<<<dim3(16, 32), 256, 0, stream>>>(W_re1, Wre1t_h, Wre1t_l, DMODEL, 512);
    cast_k<<<dim3(DMODEL * DMODEL / 1024), 256, 0, stream>>>(W_rt2, Wrt2_b, DMODEL * DMODEL);
    transcast_k<<<dim3(32, 32), 256, 0, stream>>>(W_v, Wv_t, DMODEL, DMODEL);
    transcast_k<<<dim3(32, 64), 256, 0, stream>>>(W_rt1, Wrt1_t, 2 * DMODEL, DMODEL);
    transcast_k<<<dim3(32, 32), 256, 0, stream>>>(W_o, Wo_t, DMODEL, DMODEL);
    biascomb_k<<<dim3(4), 256, 0, stream>>>(b_rt2, W_o, b_c);

    // --- encoder fast path (split-bf16 MFMA, fp32-grade) ---
    enc_gemm<<<dim3(4, 128), 256, 0, stream>>>(h_hi, h_lo, Wre1t_h, Wre1t_l, b_re1, Genc);

    hipMemsetAsync(cnt, 0, 4, stream);
    target2_k<<<dim3(MTOT / 4), 256, 0, stream>>>(Genc, W_re2, b_re2, outT, outS, gidx, cnt, list);
    // exact fp64 recompute of borderline tokens (~8%)
    fixup_k<<<dim3(4096), 256, 0, stream>>>(h, W_re1, b_re1, W_re2, b_re2, cnt, list,
                                            outT, outS, gidx);

    // --- z path ---
    mfma_gemm<EPI_TRANS_BF16, false><<<dim3(8, 8), 256, 0, stream>>>(
        Wrt2_b, Wo_t, nullptr, (void*)Wc_t, DMODEL, DMODEL, DMODEL, DMODEL, nullptr);

    mfma_gemm<EPI_BF16, false><<<dim3(8, 128), 256, 0, stream>>>(
        h_hi, Wv_t, nullptr, (void*)V, DMODEL, DMODEL, DMODEL, DMODEL, nullptr);

    mfma_gemm<EPI_GELU_BIAS_BF16, true><<<dim3(8, 128), 256, 0, stream>>>(
        V, Wrt1_t, b_rt1, (void*)G, 2 * DMODEL, DMODEL, 2 * DMODEL, DMODEL, gidx);

    mfma_gemm<EPI_BIAS_F32, false><<<dim3(8, 128), 256, 0, stream>>>(
        G, Wc_t, b_c, (void*)z, DMODEL, DMODEL, DMODEL, DMODEL, nullptr);
}